// Round 1
// 1684.504 us; speedup vs baseline: 1.2560x; 1.2560x over previous
//
#include <hip/hip_runtime.h>
#include <hip/hip_bf16.h>

#define T_TOKENS 32768
#define HID 2048
#define EPSV 1e-6f

typedef __attribute__((ext_vector_type(8))) short short8;
typedef __attribute__((ext_vector_type(4))) float f32x4;

__device__ __forceinline__ unsigned short f2bf(float f) {
    unsigned u = __float_as_uint(f);
    unsigned r = (u + 0x7fffu + ((u >> 16) & 1u)) >> 16;
    return (unsigned short)r;
}

__device__ __forceinline__ void async_copy16(const void* g, void* l) {
    __builtin_amdgcn_global_load_lds(
        (const __attribute__((address_space(1))) void*)g,
        (__attribute__((address_space(3))) void*)l,
        16, 0, 0);
}

__device__ __forceinline__ float block_sum256(float v) {
    #pragma unroll
    for (int off = 32; off > 0; off >>= 1) v += __shfl_down(v, off, 64);
    __shared__ float smem[4];
    int w = threadIdx.x >> 6;
    if ((threadIdx.x & 63) == 0) smem[w] = v;
    __syncthreads();
    return smem[0] + smem[1] + smem[2] + smem[3];
}

// ---------------- W fp32 [k][n] -> bf16 transposed [n][k] ----------------
__global__ __launch_bounds__(256)
void transpose_cast(const float* __restrict__ W, unsigned short* __restrict__ Wt) {
    __shared__ float t[32][33];
    const int bx = blockIdx.x * 32;  // n base
    const int by = blockIdx.y * 32;  // k base
    #pragma unroll
    for (int i = threadIdx.y; i < 32; i += 8)
        t[i][threadIdx.x] = W[(long)(by + i) * HID + bx + threadIdx.x];
    __syncthreads();
    #pragma unroll
    for (int i = threadIdx.y; i < 32; i += 8)
        Wt[(long)(bx + i) * HID + by + threadIdx.x] = f2bf(t[threadIdx.x][i]);
}

// ---------------- prologue: resid = relu(x); y = rmsnorm(resid, g) bf16 ----------------
__global__ __launch_bounds__(256)
void relu_rmsnorm(const float* __restrict__ x, const float* __restrict__ g,
                  float* __restrict__ resid, unsigned short* __restrict__ y) {
    const long row = blockIdx.x;
    const float4* xr = (const float4*)(x + row * HID);
    float4 v[2];
    float ssq = 0.f;
    #pragma unroll
    for (int i = 0; i < 2; ++i) {
        int c = threadIdx.x + i * 256;
        float4 t = xr[c];
        t.x = fmaxf(t.x, 0.f); t.y = fmaxf(t.y, 0.f);
        t.z = fmaxf(t.z, 0.f); t.w = fmaxf(t.w, 0.f);
        ssq += t.x * t.x + t.y * t.y + t.z * t.z + t.w * t.w;
        v[i] = t;
    }
    float tot = block_sum256(ssq);
    float scale = rsqrtf(tot * (1.f / (float)HID) + EPSV);
    float4* rr = (float4*)(resid + row * HID);
    ushort4* yr = (ushort4*)(y + row * HID);
    const float4* gg = (const float4*)g;
    #pragma unroll
    for (int i = 0; i < 2; ++i) {
        int c = threadIdx.x + i * 256;
        rr[c] = v[i];
        float4 gv = gg[c];
        ushort4 o;
        o.x = f2bf(v[i].x * scale * gv.x);
        o.y = f2bf(v[i].y * scale * gv.y);
        o.z = f2bf(v[i].z * scale * gv.z);
        o.w = f2bf(v[i].w * scale * gv.w);
        yr[c] = o;
    }
}

// ---------------- mid/final rmsnorm ----------------
__global__ __launch_bounds__(256)
void rmsnorm_stage(const float* __restrict__ resid, const float* __restrict__ g,
                   unsigned short* __restrict__ y, float* __restrict__ out, int mode) {
    const long row = blockIdx.x;
    const float4* rr = (const float4*)(resid + row * HID);
    float4 v[2];
    float ssq = 0.f;
    #pragma unroll
    for (int i = 0; i < 2; ++i) {
        int c = threadIdx.x + i * 256;
        float4 t = rr[c];
        ssq += t.x * t.x + t.y * t.y + t.z * t.z + t.w * t.w;
        v[i] = t;
    }
    float tot = block_sum256(ssq);
    float scale = rsqrtf(tot * (1.f / (float)HID) + EPSV);
    const float4* gg = (const float4*)g;
    if (mode == 0) {
        ushort4* yr = (ushort4*)(y + row * HID);
        #pragma unroll
        for (int i = 0; i < 2; ++i) {
            int c = threadIdx.x + i * 256;
            float4 gv = gg[c];
            ushort4 o;
            o.x = f2bf(v[i].x * scale * gv.x);
            o.y = f2bf(v[i].y * scale * gv.y);
            o.z = f2bf(v[i].z * scale * gv.z);
            o.w = f2bf(v[i].w * scale * gv.w);
            yr[c] = o;
        }
    } else {
        float4* orow = (float4*)(out + row * HID);
        #pragma unroll
        for (int i = 0; i < 2; ++i) {
            int c = threadIdx.x + i * 256;
            float4 gv = gg[c];
            float4 o;
            o.x = v[i].x * scale * gv.x;
            o.y = v[i].y * scale * gv.y;
            o.z = v[i].z * scale * gv.z;
            o.w = v[i].w * scale * gv.w;
            orow[c] = o;
        }
    }
}

// ======================== 256x256 8-phase GEMM ========================
// C[m][n] (resid +=) = A[M][K](bf16) @ Bt[N][K](bf16)^T, M=32768, N=K=2048.
// 512 threads = 8 waves (2M x 4N). Per-wave output: rows {wm*64..+64} u {128+wm*64..+64},
// cols {wn*32..+32} u {128+wn*32..+32}. K-tile BK=64, double-buffered by tile parity.
// LDS 128 KiB: A[par][half] 4x16KB + B[par][half] 4x16KB (half = 128 rows x 64 cols bf16).
// Swizzle: 16B slot s within a 128B row stored at s^(row&7); global_load_lds dest is
// LINEAR, the inverse permutation is applied to the global SOURCE (rule: both-sides).
// Schedule per K-tile t (par=t&1): 4 phases, each {ds_read frags | stage | s_barrier |
// lgkmcnt(0) | setprio(1) 16xMFMA setprio(0) | s_barrier}:
//   ph1 (band0,col0): read A(par,0)+B(par,0); stage A(par^1,1,t+1), B(par^1,0,t+1)
//   ph2 (band0,col1): read B(par,1);          stage A(par,0,t+2)   [A(par,0) dead after ph1]
//   ph3 (band1,col1): read A(par,1);          stage B(par,1,t+2)   [B(par,1) dead after ph2]
//   ph4 (band1,col0): read B(par,0);          vmcnt(4) [= ph2+ph3 issues in flight], barrier
// => every half of tile t+1 is issued >= 4 loads before the boundary wait: race-free,
// and loads stay in flight across barriers (counted vmcnt, never 0 mid-loop).
#define NT (HID / 64)

#define MIDBAR() do { \
    __builtin_amdgcn_sched_barrier(0); \
    __builtin_amdgcn_s_barrier(); \
    asm volatile("s_waitcnt lgkmcnt(0)" ::: "memory"); \
    __builtin_amdgcn_sched_barrier(0); \
} while (0)

#define ENDBAR() do { \
    __builtin_amdgcn_sched_barrier(0); \
    __builtin_amdgcn_s_barrier(); \
    __builtin_amdgcn_sched_barrier(0); \
} while (0)

#define LOADA(par, mb) do { \
    const char* base_ = ldsc + ((par) * 2 + (mb)) * 16384 + aRowOff; \
    _Pragma("unroll") \
    for (int mi = 0; mi < 4; ++mi) { \
        _Pragma("unroll") \
        for (int ks = 0; ks < 2; ++ks) \
            a[mi][ks] = *(const short8*)(base_ + mi * 2048 + (((ks * 4 + quad) ^ slotX) << 4)); \
    } \
} while (0)

#define LOADB(par, nb) do { \
    const char* base_ = ldsc + 65536 + ((par) * 2 + (nb)) * 16384 + bRowOff; \
    _Pragma("unroll") \
    for (int nj = 0; nj < 2; ++nj) { \
        _Pragma("unroll") \
        for (int ks = 0; ks < 2; ++ks) \
            b[nj][ks] = *(const short8*)(base_ + nj * 2048 + (((ks * 4 + quad) ^ slotX) << 4)); \
    } \
} while (0)

#define STAGEA(par, half, kt) do { \
    char* d_ = ldsc + ((par) * 2 + (half)) * 16384 + tid * 16; \
    const short* s_ = Ag + (long)(half) * (128 * HID) + (kt); \
    async_copy16(s_, d_); \
    async_copy16(s_ + 64 * HID, d_ + 8192); \
} while (0)

#define STAGEB(par, half, kt) do { \
    char* d_ = ldsc + 65536 + ((par) * 2 + (half)) * 16384 + tid * 16; \
    const short* s_ = Bg + (long)(half) * (128 * HID) + (kt); \
    async_copy16(s_, d_); \
    async_copy16(s_ + 64 * HID, d_ + 8192); \
} while (0)

#define MMAC(mb, nb) do { \
    __builtin_amdgcn_s_setprio(1); \
    _Pragma("unroll") \
    for (int mi = 0; mi < 4; ++mi) { \
        _Pragma("unroll") \
        for (int nj = 0; nj < 2; ++nj) { \
            acc[mb][mi][nb][nj] = __builtin_amdgcn_mfma_f32_16x16x32_bf16(a[mi][0], b[nj][0], acc[mb][mi][nb][nj], 0, 0, 0); \
            acc[mb][mi][nb][nj] = __builtin_amdgcn_mfma_f32_16x16x32_bf16(a[mi][1], b[nj][1], acc[mb][mi][nb][nj], 0, 0, 0); \
        } \
    } \
    __builtin_amdgcn_s_setprio(0); \
} while (0)

__global__ __launch_bounds__(512, 2)
void gemm256(const short* __restrict__ A, const short* __restrict__ Bt,
             float* __restrict__ resid) {
    extern __shared__ char ldsc[];
    const int tid = threadIdx.x;
    const int lane = tid & 63;
    const int wid = tid >> 6;
    const int wm = wid >> 2;        // 0..1  (M wave group)
    const int wn = wid & 3;         // 0..3  (N wave group)
    const int quad = lane >> 4;     // 0..3
    const int l16 = lane & 15;
    const int slotX = l16 & 7;      // read-side XOR (== row&7 of the frag row)

    // XCD-aware swizzle: grid 1024 = 8 XCD chunks of 128; each chunk = one N panel.
    const int wg = blockIdx.x;
    const int swz = (wg & 7) * 128 + (wg >> 3);
    const int bn = (swz >> 7) * 256;
    const int bm = (swz & 127) * 256;

    // staging geometry: chunk c = tid + j*512; row r = c>>3, lds slot s = c&7,
    // global slot = s ^ (r&7)  (same for j=0/1 since (r+64)&7 == r&7)
    const int srow = tid >> 3;                      // 0..63
    const int sslot = (tid & 7) ^ (srow & 7);
    const short* Ag = A + (long)(bm + srow) * HID + sslot * 8;
    const short* Bg = Bt + (long)(bn + srow) * HID + sslot * 8;

    const int aRowOff = (wm * 64 + l16) * 128;      // byte offset of frag row in region
    const int bRowOff = (wn * 32 + l16) * 128;

    short8 a[4][2], b[2][2];
    f32x4 acc[2][4][2][2] = {};   // [mband][mi][nband][nj]

    // prologue: tile 0 complete + early halves of tile 1
    STAGEA(0, 0, 0); STAGEA(0, 1, 0); STAGEB(0, 0, 0); STAGEB(0, 1, 0);
    STAGEA(1, 0, 64); STAGEB(1, 1, 64);
    asm volatile("s_waitcnt vmcnt(4)" ::: "memory");   // tile 0 landed; 4 loads in flight
    __builtin_amdgcn_s_barrier();

    for (int t = 0; t < NT; ++t) {
        const int par = t & 1;
        const int kt1 = (t + 1) * 64;
        const int kt2 = (t + 2) * 64;
        // ---- phase 1: (band0, col0) ----
        LOADA(par, 0); LOADB(par, 0);
        if (t + 1 < NT) { STAGEA(par ^ 1, 1, kt1); STAGEB(par ^ 1, 0, kt1); }
        MIDBAR();
        MMAC(0, 0);
        ENDBAR();
        // ---- phase 2: (band0, col1) ----
        LOADB(par, 1);
        if (t + 2 < NT) STAGEA(par, 0, kt2);   // A(par,0) consumed at ph1
        MIDBAR();
        MMAC(0, 1);
        ENDBAR();
        // ---- phase 3: (band1, col1) ----
        LOADA(par, 1);
        if (t + 2 < NT) STAGEB(par, 1, kt2);   // B(par,1) consumed at ph2
        MIDBAR();
        MMAC(1, 1);
        ENDBAR();
        // ---- phase 4: (band1, col0) ----
        LOADB(par, 0);
        MIDBAR();
        MMAC(1, 0);
        if (t + 2 < NT) { asm volatile("s_waitcnt vmcnt(4)" ::: "memory"); }
        else            { asm volatile("s_waitcnt vmcnt(0)" ::: "memory"); }
        ENDBAR();
    }

    // epilogue: resid += C   (C/D layout: col = lane&15, row = quad*4 + reg)
    #pragma unroll
    for (int mb = 0; mb < 2; ++mb) {
        #pragma unroll
        for (int mi = 0; mi < 4; ++mi) {
            #pragma unroll
            for (int nb = 0; nb < 2; ++nb) {
                #pragma unroll
                for (int nj = 0; nj < 2; ++nj) {
                    const int row0 = bm + mb * 128 + wm * 64 + mi * 16 + quad * 4;
                    const int col  = bn + nb * 128 + wn * 32 + nj * 16 + l16;
                    float* p = resid + (long)row0 * HID + col;
                    #pragma unroll
                    for (int r = 0; r < 4; ++r)
                        p[(long)r * HID] += acc[mb][mi][nb][nj][r];
                }
            }
        }
    }
}

extern "C" void kernel_launch(void* const* d_in, const int* in_sizes, int n_in,
                              void* d_out, int out_size, void* d_ws, size_t ws_size,
                              hipStream_t stream) {
    const float* x  = (const float*)d_in[0];
    const float* g0 = (const float*)d_in[1];
    const float* g1 = (const float*)d_in[2];
    const float* g2 = (const float*)d_in[3];
    const float* g3 = (const float*)d_in[4];
    const float* W0 = (const float*)d_in[5];
    const float* W1 = (const float*)d_in[6];
    const float* W2 = (const float*)d_in[7];
    float* out = (float*)d_out;

    // workspace layout (bf16 elements): y[T*H], Wt0[H*H], Wt1[H*H], Wt2[H*H]
    unsigned short* y   = (unsigned short*)d_ws;
    unsigned short* Wt0 = y + (size_t)T_TOKENS * HID;
    unsigned short* Wt1 = Wt0 + (size_t)HID * HID;
    unsigned short* Wt2 = Wt1 + (size_t)HID * HID;

    float* resid = out;  // d_out doubles as the fp32 residual buffer

    static int attr_done = 0;
    if (!attr_done) {
        hipFuncSetAttribute(reinterpret_cast<const void*>(gemm256),
                            hipFuncAttributeMaxDynamicSharedMemorySize, 131072);
        attr_done = 1;
    }

    dim3 tb(32, 8);
    dim3 tg(HID / 32, HID / 32);
    transpose_cast<<<tg, tb, 0, stream>>>(W0, Wt0);
    transpose_cast<<<tg, tb, 0, stream>>>(W1, Wt1);
    transpose_cast<<<tg, tb, 0, stream>>>(W2, Wt2);

    relu_rmsnorm<<<T_TOKENS, 256, 0, stream>>>(x, g0, resid, y);

    const int ngrid = (T_TOKENS / 256) * (HID / 256);  // 1024
    gemm256<<<ngrid, 512, 131072, stream>>>((const short*)y, (const short*)Wt0, resid);
    rmsnorm_stage<<<T_TOKENS, 256, 0, stream>>>(resid, g1, y, nullptr, 0);

    gemm256<<<ngrid, 512, 131072, stream>>>((const short*)y, (const short*)Wt1, resid);
    rmsnorm_stage<<<T_TOKENS, 256, 0, stream>>>(resid, g2, y, nullptr, 0);

    gemm256<<<ngrid, 512, 131072, stream>>>((const short*)y, (const short*)Wt2, resid);
    rmsnorm_stage<<<T_TOKENS, 256, 0, stream>>>(resid, g3, nullptr, out, 1);
}

// Round 2
// 1659.873 us; speedup vs baseline: 1.2747x; 1.0148x over previous
//
#include <hip/hip_runtime.h>
#include <hip/hip_bf16.h>

#define T_TOKENS 32768
#define HID 2048
#define EPSV 1e-6f

typedef __attribute__((ext_vector_type(8))) short short8;
typedef __attribute__((ext_vector_type(4))) float f32x4;

__device__ __forceinline__ unsigned short f2bf(float f) {
    unsigned u = __float_as_uint(f);
    unsigned r = (u + 0x7fffu + ((u >> 16) & 1u)) >> 16;
    return (unsigned short)r;
}

__device__ __forceinline__ void async_copy16(const void* g, void* l) {
    __builtin_amdgcn_global_load_lds(
        (const __attribute__((address_space(1))) void*)g,
        (__attribute__((address_space(3))) void*)l,
        16, 0, 0);
}

__device__ __forceinline__ float block_sum256(float v) {
    #pragma unroll
    for (int off = 32; off > 0; off >>= 1) v += __shfl_down(v, off, 64);
    __shared__ float smem[4];
    int w = threadIdx.x >> 6;
    if ((threadIdx.x & 63) == 0) smem[w] = v;
    __syncthreads();
    return smem[0] + smem[1] + smem[2] + smem[3];
}

// ---------------- W fp32 [k][n] -> bf16 transposed [n][k] ----------------
__global__ __launch_bounds__(256)
void transpose_cast(const float* __restrict__ W, unsigned short* __restrict__ Wt) {
    __shared__ float t[32][33];
    const int bx = blockIdx.x * 32;  // n base
    const int by = blockIdx.y * 32;  // k base
    #pragma unroll
    for (int i = threadIdx.y; i < 32; i += 8)
        t[i][threadIdx.x] = W[(long)(by + i) * HID + bx + threadIdx.x];
    __syncthreads();
    #pragma unroll
    for (int i = threadIdx.y; i < 32; i += 8)
        Wt[(long)(bx + i) * HID + by + threadIdx.x] = f2bf(t[threadIdx.x][i]);
}

// ---------------- prologue: resid = relu(x); y = rmsnorm(resid, g) bf16 ----------------
__global__ __launch_bounds__(256)
void relu_rmsnorm(const float* __restrict__ x, const float* __restrict__ g,
                  float* __restrict__ resid, unsigned short* __restrict__ y) {
    const long row = blockIdx.x;
    const float4* xr = (const float4*)(x + row * HID);
    float4 v[2];
    float ssq = 0.f;
    #pragma unroll
    for (int i = 0; i < 2; ++i) {
        int c = threadIdx.x + i * 256;
        float4 t = xr[c];
        t.x = fmaxf(t.x, 0.f); t.y = fmaxf(t.y, 0.f);
        t.z = fmaxf(t.z, 0.f); t.w = fmaxf(t.w, 0.f);
        ssq += t.x * t.x + t.y * t.y + t.z * t.z + t.w * t.w;
        v[i] = t;
    }
    float tot = block_sum256(ssq);
    float scale = rsqrtf(tot * (1.f / (float)HID) + EPSV);
    float4* rr = (float4*)(resid + row * HID);
    ushort4* yr = (ushort4*)(y + row * HID);
    const float4* gg = (const float4*)g;
    #pragma unroll
    for (int i = 0; i < 2; ++i) {
        int c = threadIdx.x + i * 256;
        rr[c] = v[i];
        float4 gv = gg[c];
        ushort4 o;
        o.x = f2bf(v[i].x * scale * gv.x);
        o.y = f2bf(v[i].y * scale * gv.y);
        o.z = f2bf(v[i].z * scale * gv.z);
        o.w = f2bf(v[i].w * scale * gv.w);
        yr[c] = o;
    }
}

// ---------------- mid/final rmsnorm ----------------
__global__ __launch_bounds__(256)
void rmsnorm_stage(const float* __restrict__ resid, const float* __restrict__ g,
                   unsigned short* __restrict__ y, float* __restrict__ out, int mode) {
    const long row = blockIdx.x;
    const float4* rr = (const float4*)(resid + row * HID);
    float4 v[2];
    float ssq = 0.f;
    #pragma unroll
    for (int i = 0; i < 2; ++i) {
        int c = threadIdx.x + i * 256;
        float4 t = rr[c];
        ssq += t.x * t.x + t.y * t.y + t.z * t.z + t.w * t.w;
        v[i] = t;
    }
    float tot = block_sum256(ssq);
    float scale = rsqrtf(tot * (1.f / (float)HID) + EPSV);
    const float4* gg = (const float4*)g;
    if (mode == 0) {
        ushort4* yr = (ushort4*)(y + row * HID);
        #pragma unroll
        for (int i = 0; i < 2; ++i) {
            int c = threadIdx.x + i * 256;
            float4 gv = gg[c];
            ushort4 o;
            o.x = f2bf(v[i].x * scale * gv.x);
            o.y = f2bf(v[i].y * scale * gv.y);
            o.z = f2bf(v[i].z * scale * gv.z);
            o.w = f2bf(v[i].w * scale * gv.w);
            yr[c] = o;
        }
    } else {
        float4* orow = (float4*)(out + row * HID);
        #pragma unroll
        for (int i = 0; i < 2; ++i) {
            int c = threadIdx.x + i * 256;
            float4 gv = gg[c];
            float4 o;
            o.x = v[i].x * scale * gv.x;
            o.y = v[i].y * scale * gv.y;
            o.z = v[i].z * scale * gv.z;
            o.w = v[i].w * scale * gv.w;
            orow[c] = o;
        }
    }
}

// ======================== 256x256 GEMM, minimal-barrier 3-region schedule ========================
// C[m][n] (resid +=) = A[M][K](bf16) @ Bt[N][K](bf16)^T.
// 512 threads = 8 waves (2M x 4N). Per-wave output 128x64 (2 row-bands x 2 col-bands).
// LDS 128 KiB, double-buffered by K-tile parity; BK=64; regions A/B x par x half, 16KB each.
// Swizzle: 16B slot s within a 128B row stored at s^(row&7); global_load_lds dest LINEAR,
// inverse permutation applied to the global SOURCE; ds_read applies the XOR on the slot.
//
// Sync derivation (per K-tile, 3 barriers only):
//  - restage region R only after ALL waves' ds_reads of R retired:
//      [MFMA cluster consumes reads] -> lgkmcnt(0) (free: already retired) -> s_barrier -> stage
//  - read freshly staged region only after its loads landed everywhere:
//      boundary vmcnt(4) (counted: ph2/ph3 stages stay in flight) -> s_barrier -> sched_barrier
//  - NO blocking lgkm before MFMA: compiler emits fine-grained counted lgkm waits per operand.
// FIFO check: region-1 stages (tile t+1 data) retire at tile t's vmcnt(4) because region-2/3
// stages (tile t+2 data) are the 4 newest. Tail (t+2>=NT): vmcnt(0) drains everything.
//
// MFMA operand order is SWAPPED (mfma(b,a,acc)) so the C/D fragment is transposed:
// lane holds row = l16, cols = quad*4 + r (4 consecutive) -> float4 RMW epilogue.
#define NT (HID / 64)

#define LOADA(par, mb) do { \
    const char* base_ = ldsc + ((par) * 2 + (mb)) * 16384 + aRowOff; \
    _Pragma("unroll") \
    for (int mi = 0; mi < 4; ++mi) { \
        _Pragma("unroll") \
        for (int ks = 0; ks < 2; ++ks) \
            a[mi][ks] = *(const short8*)(base_ + mi * 2048 + (((ks * 4 + quad) ^ slotX) << 4)); \
    } \
} while (0)

#define LOADB(par, nb) do { \
    const char* base_ = ldsc + 65536 + ((par) * 2 + (nb)) * 16384 + bRowOff; \
    _Pragma("unroll") \
    for (int nj = 0; nj < 2; ++nj) { \
        _Pragma("unroll") \
        for (int ks = 0; ks < 2; ++ks) \
            b[nj][ks] = *(const short8*)(base_ + nj * 2048 + (((ks * 4 + quad) ^ slotX) << 4)); \
    } \
} while (0)

#define STAGEA(par, half, kt) do { \
    char* d_ = ldsc + ((par) * 2 + (half)) * 16384 + tid * 16; \
    const short* s_ = Ag + (long)(half) * (128 * HID) + (kt); \
    async_copy16(s_, d_); \
    async_copy16(s_ + 64 * HID, d_ + 8192); \
} while (0)

#define STAGEB(par, half, kt) do { \
    char* d_ = ldsc + 65536 + ((par) * 2 + (half)) * 16384 + tid * 16; \
    const short* s_ = Bg + (long)(half) * (128 * HID) + (kt); \
    async_copy16(s_, d_); \
    async_copy16(s_ + 64 * HID, d_ + 8192); \
} while (0)

// swapped operands: acc fragment is C^T-layout (lane: row=l16, cols=quad*4+reg)
#define MMAC(mb, nb) do { \
    __builtin_amdgcn_s_setprio(1); \
    _Pragma("unroll") \
    for (int mi = 0; mi < 4; ++mi) { \
        _Pragma("unroll") \
        for (int nj = 0; nj < 2; ++nj) { \
            acc[mb][mi][nb][nj] = __builtin_amdgcn_mfma_f32_16x16x32_bf16(b[nj][0], a[mi][0], acc[mb][mi][nb][nj], 0, 0, 0); \
            acc[mb][mi][nb][nj] = __builtin_amdgcn_mfma_f32_16x16x32_bf16(b[nj][1], a[mi][1], acc[mb][mi][nb][nj], 0, 0, 0); \
        } \
    } \
    __builtin_amdgcn_s_setprio(0); \
} while (0)

#define DRAIN_BAR() do { \
    asm volatile("s_waitcnt lgkmcnt(0)" ::: "memory"); \
    __builtin_amdgcn_s_barrier(); \
} while (0)

__global__ __launch_bounds__(512, 2)
void gemm256(const short* __restrict__ A, const short* __restrict__ Bt,
             float* __restrict__ resid) {
    extern __shared__ char ldsc[];
    const int tid = threadIdx.x;
    const int lane = tid & 63;
    const int wid = tid >> 6;
    const int wm = wid >> 2;        // 0..1  (M wave group)
    const int wn = wid & 3;         // 0..3  (N wave group)
    const int quad = lane >> 4;     // 0..3
    const int l16 = lane & 15;
    const int slotX = l16 & 7;      // read-side XOR (== row&7 of the frag row)

    // XCD-aware swizzle: grid 1024 = 8 XCD chunks of 128; each chunk = one N panel.
    const int wg = blockIdx.x;
    const int swz = (wg & 7) * 128 + (wg >> 3);
    const int bn = (swz >> 7) * 256;
    const int bm = (swz & 127) * 256;

    // staging geometry: chunk c = tid + j*512; row r = c>>3, lds slot s = c&7,
    // global slot = s ^ (r&7)  (same for j=0/1 since (r+64)&7 == r&7)
    const int srow = tid >> 3;                      // 0..63
    const int sslot = (tid & 7) ^ (srow & 7);
    const short* Ag = A + (long)(bm + srow) * HID + sslot * 8;
    const short* Bg = Bt + (long)(bn + srow) * HID + sslot * 8;

    const int aRowOff = (wm * 64 + l16) * 128;      // byte offset of frag row in region
    const int bRowOff = (wn * 32 + l16) * 128;

    short8 a[4][2], b[2][2];
    f32x4 acc[2][4][2][2] = {};   // [mband][mi][nband][nj]

    // prologue: tile 0 complete + the tile-1 halves that steady state staged "at t=-1"
    STAGEA(0, 0, 0); STAGEA(0, 1, 0); STAGEB(0, 0, 0); STAGEB(0, 1, 0);
    STAGEA(1, 0, 64); STAGEB(1, 1, 64);
    asm volatile("s_waitcnt vmcnt(4)" ::: "memory");   // tile 0 landed; 4 loads in flight
    __builtin_amdgcn_s_barrier();
    __builtin_amdgcn_sched_barrier(0);

    for (int t = 0; t < NT; ++t) {
        const int par = t & 1;
        const int kt1 = (t + 1) * 64;
        const int kt2 = (t + 2) * 64;
        // ---- region 1: quadrant (band0, col0) ----
        LOADA(par, 0); LOADB(par, 0);
        if (t + 1 < NT) { STAGEA(par ^ 1, 1, kt1); STAGEB(par ^ 1, 0, kt1); }
        MMAC(0, 0);
        DRAIN_BAR();                       // A(par,0) readers drained everywhere
        // ---- region 2: quadrant (band0, col1) ----
        if (t + 2 < NT) STAGEA(par, 0, kt2);
        LOADB(par, 1);
        MMAC(0, 1);
        DRAIN_BAR();                       // B(par,1) readers drained everywhere
        // ---- region 3: quadrants (band1, col1) then (band1, col0) ----
        if (t + 2 < NT) STAGEB(par, 1, kt2);
        LOADA(par, 1);
        MMAC(1, 1);
        LOADB(par, 0);
        MMAC(1, 0);
        asm volatile("s_waitcnt lgkmcnt(0)" ::: "memory");
        if (t + 2 < NT) { asm volatile("s_waitcnt vmcnt(4)" ::: "memory"); }
        else            { asm volatile("s_waitcnt vmcnt(0)" ::: "memory"); }
        __builtin_amdgcn_s_barrier();      // boundary: next tile's buffer fully landed
        __builtin_amdgcn_sched_barrier(0);
    }

    // epilogue: resid += C, vectorized float4 RMW (transposed acc layout)
    #pragma unroll
    for (int mb = 0; mb < 2; ++mb) {
        #pragma unroll
        for (int mi = 0; mi < 4; ++mi) {
            const int row = bm + mb * 128 + wm * 64 + mi * 16 + l16;
            float* prow = resid + (long)row * HID + bn;
            #pragma unroll
            for (int nb = 0; nb < 2; ++nb) {
                #pragma unroll
                for (int nj = 0; nj < 2; ++nj) {
                    const int col = nb * 128 + wn * 32 + nj * 16 + quad * 4;
                    f32x4* p = (f32x4*)(prow + col);
                    f32x4 c = *p;
                    c += acc[mb][mi][nb][nj];
                    *p = c;
                }
            }
        }
    }
}

extern "C" void kernel_launch(void* const* d_in, const int* in_sizes, int n_in,
                              void* d_out, int out_size, void* d_ws, size_t ws_size,
                              hipStream_t stream) {
    const float* x  = (const float*)d_in[0];
    const float* g0 = (const float*)d_in[1];
    const float* g1 = (const float*)d_in[2];
    const float* g2 = (const float*)d_in[3];
    const float* g3 = (const float*)d_in[4];
    const float* W0 = (const float*)d_in[5];
    const float* W1 = (const float*)d_in[6];
    const float* W2 = (const float*)d_in[7];
    float* out = (float*)d_out;

    // workspace layout (bf16 elements): y[T*H], Wt0[H*H], Wt1[H*H], Wt2[H*H]
    unsigned short* y   = (unsigned short*)d_ws;
    unsigned short* Wt0 = y + (size_t)T_TOKENS * HID;
    unsigned short* Wt1 = Wt0 + (size_t)HID * HID;
    unsigned short* Wt2 = Wt1 + (size_t)HID * HID;

    float* resid = out;  // d_out doubles as the fp32 residual buffer

    static int attr_done = 0;
    if (!attr_done) {
        hipFuncSetAttribute(reinterpret_cast<const void*>(gemm256),
                            hipFuncAttributeMaxDynamicSharedMemorySize, 131072);
        attr_done = 1;
    }

    dim3 tb(32, 8);
    dim3 tg(HID / 32, HID / 32);
    transpose_cast<<<tg, tb, 0, stream>>>(W0, Wt0);
    transpose_cast<<<tg, tb, 0, stream>>>(W1, Wt1);
    transpose_cast<<<tg, tb, 0, stream>>>(W2, Wt2);

    relu_rmsnorm<<<T_TOKENS, 256, 0, stream>>>(x, g0, resid, y);

    const int ngrid = (T_TOKENS / 256) * (HID / 256);  // 1024
    gemm256<<<ngrid, 512, 131072, stream>>>((const short*)y, (const short*)Wt0, resid);
    rmsnorm_stage<<<T_TOKENS, 256, 0, stream>>>(resid, g1, y, nullptr, 0);

    gemm256<<<ngrid, 512, 131072, stream>>>((const short*)y, (const short*)Wt1, resid);
    rmsnorm_stage<<<T_TOKENS, 256, 0, stream>>>(resid, g2, y, nullptr, 0);

    gemm256<<<ngrid, 512, 131072, stream>>>((const short*)y, (const short*)Wt2, resid);
    rmsnorm_stage<<<T_TOKENS, 256, 0, stream>>>(resid, g3, nullptr, out, 1);
}